// Round 1
// baseline (96.735 us; speedup 1.0000x reference)
//
#include <hip/hip_runtime.h>

#define HD  16    // hidden_dim
#define DIM 256   // query dim
#define NW  65    // 4*HD+1 weights per box
#define HW  64    // grid H=W

// One block per box n:
//   phase 1: stage q[n,:] into LDS; threads 0..64 compute weights[n,j] = bg[j] + sum_d q*Wg
//   phase 2: render 64x64 MLP output; thread owns 4 consecutive x, 4 row-iterations
__global__ __launch_bounds__(256, 4) void posmlp_kernel(
    const float* __restrict__ pos,      // (N,4)
    const float* __restrict__ queries,  // (N,DIM)
    const float* __restrict__ Wg,       // (DIM,NW)
    const float* __restrict__ bg,       // (NW)
    float* __restrict__ out)            // (N,HW,HW)
{
    const int n   = blockIdx.x;
    const int tid = threadIdx.x;

    __shared__ float qs[DIM];
    __shared__ float wl[NW];

    // ---- phase 1: weights = q @ Wg + bg (per box) ----
    qs[tid] = queries[n * DIM + tid];
    __syncthreads();

    if (tid < NW) {
        float acc = bg[tid];
        #pragma unroll 8
        for (int d = 0; d < DIM; ++d)
            acc = fmaf(qs[d], Wg[d * NW + tid], acc);   // Wg coalesced across j
        wl[tid] = acc;
    }
    __syncthreads();

    // ---- phase 2: render ----
    const float cx = pos[n * 4 + 0];
    const float cy = pos[n * 4 + 1];
    const float inv_bw = 1.0f / pos[n * 4 + 2];
    const float inv_bh = 1.0f / pos[n * 4 + 3];

    float w1x[HD], w1y[HD], b1[HD], w2[HD];
    #pragma unroll
    for (int k = 0; k < HD; ++k) {
        w1x[k] = wl[k];
        w1y[k] = wl[HD + k];
        b1[k]  = wl[2 * HD + k];
        w2[k]  = wl[3 * HD + k];
    }
    const float b2 = wl[4 * HD];

    const int xg = tid & 15;   // x-group: owns x0..x0+3
    const int yl = tid >> 4;   // 0..15
    const int x0 = xg * 4;

    // per-x part: ax[j][k] = rel_x(x0+j) * w1x[k]   (hoisted, reused over 64 rows/4 iters)
    float ax[4][HD];
    #pragma unroll
    for (int j = 0; j < 4; ++j) {
        const float rx = ((x0 + j + 0.5f) * (1.0f / HW) - cx) * inv_bw;
        #pragma unroll
        for (int k = 0; k < HD; ++k)
            ax[j][k] = rx * w1x[k];
    }

    float* outn = out + (size_t)n * (HW * HW);

    #pragma unroll
    for (int it = 0; it < 4; ++it) {
        const int y = it * 16 + yl;
        const float ry = ((y + 0.5f) * (1.0f / HW) - cy) * inv_bh;

        float ayb[HD];
        #pragma unroll
        for (int k = 0; k < HD; ++k)
            ayb[k] = fmaf(ry, w1y[k], b1[k]);

        float4 acc = make_float4(b2, b2, b2, b2);
        #pragma unroll
        for (int k = 0; k < HD; ++k) {
            const float t0 = fmaxf(ax[0][k] + ayb[k], 0.0f);
            const float t1 = fmaxf(ax[1][k] + ayb[k], 0.0f);
            const float t2 = fmaxf(ax[2][k] + ayb[k], 0.0f);
            const float t3 = fmaxf(ax[3][k] + ayb[k], 0.0f);
            acc.x = fmaf(t0, w2[k], acc.x);
            acc.y = fmaf(t1, w2[k], acc.y);
            acc.z = fmaf(t2, w2[k], acc.z);
            acc.w = fmaf(t3, w2[k], acc.w);
        }
        *reinterpret_cast<float4*>(outn + y * HW + x0) = acc;
    }
}

extern "C" void kernel_launch(void* const* d_in, const int* in_sizes, int n_in,
                              void* d_out, int out_size, void* d_ws, size_t ws_size,
                              hipStream_t stream) {
    const float* pos = (const float*)d_in[0];
    const float* q   = (const float*)d_in[1];
    const float* Wg  = (const float*)d_in[2];
    const float* bg  = (const float*)d_in[3];
    float* out = (float*)d_out;

    const int N = in_sizes[0] / 4;   // 8*300 = 2400 boxes
    posmlp_kernel<<<N, 256, 0, stream>>>(pos, q, Wg, bg, out);
}

// Round 2
// 96.184 us; speedup vs baseline: 1.0057x; 1.0057x over previous
//
#include <hip/hip_runtime.h>

#define HD  16    // hidden_dim
#define DIM 256   // query dim
#define NW  65    // 4*HD+1 weights per box
#define HW  64    // grid H=W

// One block per box n:
//   phase 1: stage q[n,:] into LDS; threads 0..64 compute weights[n,j] = bg[j] + sum_d q*Wg
//   phase 2: render 64x64 MLP output; thread owns 4 consecutive x, 4 row-iterations.
//   Key: pre = rx*w1x[k] + (ry*w1y[k] + b1[k]) -> single fmaf against per-row ayb[k];
//   no per-thread ax[4][16] array -> ~100 live VGPRs, no spill at the 128 cap.
__global__ __launch_bounds__(256, 4) void posmlp_kernel(
    const float* __restrict__ pos,      // (N,4)
    const float* __restrict__ queries,  // (N,DIM)
    const float* __restrict__ Wg,       // (DIM,NW)
    const float* __restrict__ bg,       // (NW)
    float* __restrict__ out)            // (N,HW,HW)
{
    const int n   = blockIdx.x;
    const int tid = threadIdx.x;

    __shared__ float qs[DIM];
    __shared__ float wl[NW];

    // ---- phase 1: weights = q @ Wg + bg (per box) ----
    qs[tid] = queries[n * DIM + tid];
    __syncthreads();

    if (tid < NW) {
        float a0 = 0.f, a1 = 0.f, a2 = 0.f, a3 = 0.f;   // 4-way ILP on the dot
        #pragma unroll 4
        for (int d = 0; d < DIM; d += 4) {
            a0 = fmaf(qs[d + 0], Wg[(d + 0) * NW + tid], a0);
            a1 = fmaf(qs[d + 1], Wg[(d + 1) * NW + tid], a1);
            a2 = fmaf(qs[d + 2], Wg[(d + 2) * NW + tid], a2);
            a3 = fmaf(qs[d + 3], Wg[(d + 3) * NW + tid], a3);
        }
        wl[tid] = bg[tid] + ((a0 + a1) + (a2 + a3));
    }
    __syncthreads();

    // ---- phase 2: render ----
    const float cx = pos[n * 4 + 0];
    const float cy = pos[n * 4 + 1];
    const float inv_bw = 1.0f / pos[n * 4 + 2];
    const float inv_bh = 1.0f / pos[n * 4 + 3];

    float w1x[HD], w1y[HD], b1[HD], w2[HD];
    #pragma unroll
    for (int k = 0; k < HD; ++k) {
        w1x[k] = wl[k];
        w1y[k] = wl[HD + k];
        b1[k]  = wl[2 * HD + k];
        w2[k]  = wl[3 * HD + k];
    }
    const float b2 = wl[4 * HD];

    const int xg = tid & 15;   // x-group: owns x0..x0+3
    const int yl = tid >> 4;   // 0..15
    const int x0 = xg * 4;

    float rx[4];
    #pragma unroll
    for (int j = 0; j < 4; ++j)
        rx[j] = ((x0 + j + 0.5f) * (1.0f / HW) - cx) * inv_bw;

    float* outn = out + (size_t)n * (HW * HW);

    #pragma unroll
    for (int it = 0; it < 4; ++it) {
        const int y = it * 16 + yl;
        const float ry = ((y + 0.5f) * (1.0f / HW) - cy) * inv_bh;

        float ayb[HD];
        #pragma unroll
        for (int k = 0; k < HD; ++k)
            ayb[k] = fmaf(ry, w1y[k], b1[k]);

        float4 acc = make_float4(b2, b2, b2, b2);
        #pragma unroll
        for (int k = 0; k < HD; ++k) {
            const float t0 = fmaxf(fmaf(rx[0], w1x[k], ayb[k]), 0.0f);
            const float t1 = fmaxf(fmaf(rx[1], w1x[k], ayb[k]), 0.0f);
            const float t2 = fmaxf(fmaf(rx[2], w1x[k], ayb[k]), 0.0f);
            const float t3 = fmaxf(fmaf(rx[3], w1x[k], ayb[k]), 0.0f);
            acc.x = fmaf(t0, w2[k], acc.x);
            acc.y = fmaf(t1, w2[k], acc.y);
            acc.z = fmaf(t2, w2[k], acc.z);
            acc.w = fmaf(t3, w2[k], acc.w);
        }
        *reinterpret_cast<float4*>(outn + y * HW + x0) = acc;
    }
}

extern "C" void kernel_launch(void* const* d_in, const int* in_sizes, int n_in,
                              void* d_out, int out_size, void* d_ws, size_t ws_size,
                              hipStream_t stream) {
    const float* pos = (const float*)d_in[0];
    const float* q   = (const float*)d_in[1];
    const float* Wg  = (const float*)d_in[2];
    const float* bg  = (const float*)d_in[3];
    float* out = (float*)d_out;

    const int N = in_sizes[0] / 4;   // 8*300 = 2400 boxes
    posmlp_kernel<<<N, 256, 0, stream>>>(pos, q, Wg, bg, out);
}